// Round 11
// baseline (52.794 us; speedup 1.0000x reference)
//
#include <hip/hip_runtime.h>
#include <hip/hip_bf16.h>

typedef __attribute__((ext_vector_type(8))) short  short8_t;
typedef __attribute__((ext_vector_type(4))) float  float4_t;
typedef __attribute__((ext_vector_type(4))) int    int4_t;
typedef __attribute__((ext_vector_type(2))) unsigned int uint2_t;

// f32 -> bf16 RNE (bit-twiddle; prepass/fallback only)
__device__ __forceinline__ unsigned short f2bf(float f) {
    unsigned int u = __builtin_bit_cast(unsigned int, f);
    u += 0x7FFFu + ((u >> 16) & 1u);
    return (unsigned short)(u >> 16);
}
__device__ __forceinline__ unsigned int cvtpk(float a, float b) {
    return (unsigned int)f2bf(a) | ((unsigned int)f2bf(b) << 16);
}
// HW packed convert (no builtin on gfx950)
__device__ __forceinline__ unsigned int cvtpk_hw(float a, float b) {
    unsigned int r;
    asm("v_cvt_pk_bf16_f32 %0, %1, %2" : "=v"(r) : "v"(a), "v"(b));
    return r;
}
// pinned 16B load the compiler cannot sink (T4 building block)
__device__ __forceinline__ void gld16(int4_t& d, const void* p) {
    asm volatile("global_load_dwordx4 %0, %1, off" : "=&v"(d) : "v"(p) : "memory");
}
// 2-deep pipeline wait: the 2 younger sets (8 loads) stay in flight
__device__ __forceinline__ void wait8() {
    asm volatile("s_waitcnt vmcnt(8)" ::: "memory");
    __builtin_amdgcn_sched_barrier(0);
}
// full drain before epilogue (async asm loads must land before regalloc reuse)
__device__ __forceinline__ void wait_all() {
    asm volatile("s_waitcnt vmcnt(0)" ::: "memory");
    __builtin_amdgcn_sched_barrier(0);
}

#define W1ROWS 1088   // 1024 + 64 zero-pad rows

// ---- prepass: W2 -> granule-transposed bf16 W2s[ks][e]; W1 -> bf16 W1b (+zero pad) ----
__global__ void prep_kernel(const float* __restrict__ W2, const float* __restrict__ W1,
                            unsigned short* __restrict__ W2s, unsigned short* __restrict__ W1b) {
    const int bid = blockIdx.x, tid = threadIdx.x;
    if (bid < 128) {
        const int idx = bid * 256 + tid;
        const int e   = idx >> 7;
        const int ks  = idx & 127;
        const float* src = W2 + (size_t)e * 1024 + ks * 8;
        const float4_t v0 = *reinterpret_cast<const float4_t*>(src);
        const float4_t v1 = *reinterpret_cast<const float4_t*>(src + 4);
        int4_t p;
        p[0] = (int)cvtpk(v0[0], v0[1]);
        p[1] = (int)cvtpk(v0[2], v0[3]);
        p[2] = (int)cvtpk(v1[0], v1[1]);
        p[3] = (int)cvtpk(v1[2], v1[3]);
        *reinterpret_cast<int4_t*>(W2s + ((size_t)ks * 256 + e) * 8) = p;
    } else {
        const int base = tid * 32;
        #pragma unroll
        for (int it = 0; it < 8; ++it) {
            const float4_t v = *reinterpret_cast<const float4_t*>(W1 + base + it * 4);
            uint2_t p;
            p[0] = cvtpk(v[0], v[1]);
            p[1] = cvtpk(v[2], v[3]);
            *reinterpret_cast<uint2_t*>(W1b + base + it * 4) = p;
        }
        if (tid < 16) {
            #pragma unroll
            for (int it = 0; it < 4; ++it) {
                int4_t z; z[0] = 0; z[1] = 0; z[2] = 0; z[3] = 0;
                *reinterpret_cast<int4_t*>(W1b + 8192 + tid * 32 + it * 8) = z;
            }
        }
    }
}

// ---- fused: per-block h computed ONCE into LDS (A-frag layout), then barrier-free
//      main GEMM with asm-pinned bf pipeline. Block = 16 rows x 256 cols, 4 waves.
template <bool WSOK>
__global__ __launch_bounds__(256, 4)
void ffq_kernel(const float* __restrict__ x,
                const float* __restrict__ theta,
                const float* __restrict__ W1f,
                const unsigned short* __restrict__ W1b,
                const float* __restrict__ W2f,
                const unsigned short* __restrict__ W2s,
                float* __restrict__ out)
{
    // h in MFMA-A-fragment layout: h_lds[ks][m][j]  (k-granule ks = f/8) -> 32 KB
    __shared__ __align__(16) unsigned short h_lds[128][16][8];

    const int tid  = threadIdx.x;
    const int lane = tid & 63;
    const int w    = tid >> 6;
    const int bid  = blockIdx.x;
    const int rowbase = bid * 16;        // 2048 blocks x 16 rows
    const int colbase = w * 64;          // wave covers one 64-col quarter
    const int lr = lane & 15;
    const int G  = lane >> 4;

    // ---- q B-frag (block's 16 rows): lane<16 holds q[row][k=0..7], rest zero ----
    short8_t qf = {0,0,0,0,0,0,0,0};
    if (lane < 16) {
        const float* xp = x + (size_t)(rowbase + lane) * 256;
        const float4_t x0 = *reinterpret_cast<const float4_t*>(xp);
        const float4_t x1 = *reinterpret_cast<const float4_t*>(xp + 4);
        float qv[8];
        #pragma unroll
        for (int j = 0; j < 4; ++j) {
            qv[j]     = __cosf(x0[j]) * __cosf(theta[j]);
            qv[4 + j] = __cosf(x1[j]) * __cosf(theta[4 + j]);
        }
        int4_t pq;
        pq[0] = (int)cvtpk(qv[0], qv[1]);
        pq[1] = (int)cvtpk(qv[2], qv[3]);
        pq[2] = (int)cvtpk(qv[4], qv[5]);
        pq[3] = (int)cvtpk(qv[6], qv[7]);
        qf = __builtin_bit_cast(short8_t, pq);
    }

    // ---- h-phase: wave w computes f-quarter [w*256, w*256+256): 16 f-tiles of 16 ----
    // D (m=lane&15, f=ftile*16+4G+r) -> relu -> bf16 pair -> ds_write_b64 straight
    // into A-frag layout: h_lds[2*fg + (G>>1)][m][(G&1)*4 .. +3]
    #pragma unroll
    for (int ft = 0; ft < 16; ++ft) {
        const int fg = w * 16 + ft;              // global f-tile 0..63
        short8_t af;
        if constexpr (WSOK) {
            // lane (row f = fg*16+lr, granule G): 16B from W1b row-major (G>=1 reads
            // neighbor rows = finite garbage, annihilated by qf's zero k-groups)
            af = *reinterpret_cast<const short8_t*>(W1b + ((size_t)(fg * 16 + lr) * 8 + G * 8));
        } else {
            const float* src = W1f + (size_t)(fg * 16 + lr) * 8;   // same addr all G (finite)
            const float4_t v0 = *reinterpret_cast<const float4_t*>(src);
            const float4_t v1 = *reinterpret_cast<const float4_t*>(src + 4);
            int4_t p;
            p[0] = (int)cvtpk(v0[0], v0[1]);
            p[1] = (int)cvtpk(v0[2], v0[3]);
            p[2] = (int)cvtpk(v1[0], v1[1]);
            p[3] = (int)cvtpk(v1[2], v1[3]);
            af = __builtin_bit_cast(short8_t, p);
        }
        const float4_t d = __builtin_amdgcn_mfma_f32_16x16x32_bf16(
            af, qf, (float4_t){0.f, 0.f, 0.f, 0.f}, 0, 0, 0);
        uint2_t pk;
        pk[0] = cvtpk_hw(fmaxf(d[0], 0.f), fmaxf(d[1], 0.f));
        pk[1] = cvtpk_hw(fmaxf(d[2], 0.f), fmaxf(d[3], 0.f));
        *reinterpret_cast<uint2_t*>(&h_lds[2 * fg + (G >> 1)][lr][(G & 1) * 4]) = pk;
    }

    __syncthreads();   // h published; also drains all compiler vmem (exact asm counts below)

    float4_t acc[4];
    #pragma unroll
    for (int j = 0; j < 4; ++j) acc[j] = (float4_t){0.f, 0.f, 0.f, 0.f};

    if constexpr (WSOK) {
        auto b_addr = [&](int kc, int cf) -> const void* {
            const int e = colbase + cf * 16 + lr;
            return (const void*)(W2s + (((size_t)(kc >> 3) + G) * 256 + e) * 8);
        };
        int4_t Ab0, Ab1, Ab2, Ab3;
        int4_t Bb0, Bb1, Bb2, Bb3;
        int4_t Cb0, Cb1, Cb2, Cb3;
        int4_t Db0, Db1, Db2, Db3;

        #define ISSUE(P, K) do { const int kk_ = (K) & 1023;                \
            gld16(P##b0, b_addr(kk_, 0)); gld16(P##b1, b_addr(kk_, 1));     \
            gld16(P##b2, b_addr(kk_, 2)); gld16(P##b3, b_addr(kk_, 3)); } while (0)
        // afn = A-frag for the NEXT chunk (ds_read prefetched one chunk ahead)
        #define COMPUTE(P, KC) do {                                                      \
            const short8_t afu = afn;                                                    \
            afn = *reinterpret_cast<const short8_t*>(                                    \
                &h_lds[((((KC) + 32) & 1023) >> 3) + G][lr][0]);                         \
            acc[0] = __builtin_amdgcn_mfma_f32_16x16x32_bf16(                            \
                afu, __builtin_bit_cast(short8_t, P##b0), acc[0], 0, 0, 0);              \
            acc[1] = __builtin_amdgcn_mfma_f32_16x16x32_bf16(                            \
                afu, __builtin_bit_cast(short8_t, P##b1), acc[1], 0, 0, 0);              \
            acc[2] = __builtin_amdgcn_mfma_f32_16x16x32_bf16(                            \
                afu, __builtin_bit_cast(short8_t, P##b2), acc[2], 0, 0, 0);              \
            acc[3] = __builtin_amdgcn_mfma_f32_16x16x32_bf16(                            \
                afu, __builtin_bit_cast(short8_t, P##b3), acc[3], 0, 0, 0); } while (0)

        short8_t afn = *reinterpret_cast<const short8_t*>(&h_lds[G][lr][0]);  // chunk 0
        ISSUE(A, 0);
        ISSUE(B, 32);
        #pragma unroll 1
        for (int kc = 0; kc < 1024; kc += 128) {
            ISSUE(C, kc + 64);  wait8(); COMPUTE(A, kc);
            ISSUE(D, kc + 96);  wait8(); COMPUTE(B, kc + 32);
            ISSUE(A, kc + 128); wait8(); COMPUTE(C, kc + 64);   // wraps on last iter
            ISSUE(B, kc + 160); wait8(); COMPUTE(D, kc + 96);   // wraps on last iter
        }
        wait_all();   // land dangling wrap prefetches before regalloc reuses their regs
        #undef ISSUE
        #undef COMPUTE
    } else {
        // fallback (no workspace): compiler-scheduled, correctness-first
        for (int kc = 0; kc < 1024; kc += 32) {
            const short8_t af = *reinterpret_cast<const short8_t*>(&h_lds[(kc >> 3) + G][lr][0]);
            #pragma unroll
            for (int cf = 0; cf < 4; ++cf) {
                const int e = colbase + cf * 16 + lr;
                const float* p = W2f + (size_t)e * 1024 + kc + G * 8;
                const float4_t v0 = *reinterpret_cast<const float4_t*>(p);
                const float4_t v1 = *reinterpret_cast<const float4_t*>(p + 4);
                int4_t pb;
                pb[0] = (int)cvtpk(v0[0], v0[1]);
                pb[1] = (int)cvtpk(v0[2], v0[3]);
                pb[2] = (int)cvtpk(v1[0], v1[1]);
                pb[3] = (int)cvtpk(v1[2], v1[3]);
                acc[cf] = __builtin_amdgcn_mfma_f32_16x16x32_bf16(
                    af, __builtin_bit_cast(short8_t, pb), acc[cf], 0, 0, 0);
            }
        }
    }

    // ---- epilogue: C/D layout col=lane&15 (e), row=(lane>>4)*4+reg (m) ----
    #pragma unroll
    for (int cf = 0; cf < 4; ++cf)
        #pragma unroll
        for (int r = 0; r < 4; ++r) {
            const int gr = rowbase + G * 4 + r;
            const int gc = colbase + cf * 16 + lr;
            out[(size_t)gr * 256 + gc] = acc[cf][r];
        }
}

extern "C" void kernel_launch(void* const* d_in, const int* in_sizes, int n_in,
                              void* d_out, int out_size, void* d_ws, size_t ws_size,
                              hipStream_t stream) {
    const float* x     = (const float*)d_in[0];   // [8,4096,256]
    const float* theta = (const float*)d_in[1];   // [8]
    const float* W1    = (const float*)d_in[2];   // [1024,8]
    const float* W2    = (const float*)d_in[3];   // [256,1024]
    float* out = (float*)d_out;                   // [8,4096,256] f32

    const size_t need = (size_t)(256 * 1024 + W1ROWS * 8) * sizeof(unsigned short);
    const bool wsok = (ws_size >= need);

    if (wsok) {
        unsigned short* W2s = (unsigned short*)d_ws;   // 512KB granule-transposed bf16
        unsigned short* W1b = W2s + 256 * 1024;        // 1088x8 bf16 (pad rows zeroed)
        prep_kernel<<<129, 256, 0, stream>>>(W2, W1, W2s, W1b);
        ffq_kernel<true><<<2048, 256, 0, stream>>>(x, theta, nullptr, W1b, nullptr, W2s, out);
    } else {
        ffq_kernel<false><<<2048, 256, 0, stream>>>(x, theta, W1, nullptr, W2, nullptr, out);
    }
}

// Round 12
// 39.994 us; speedup vs baseline: 1.3200x; 1.3200x over previous
//
#include <hip/hip_runtime.h>
#include <hip/hip_bf16.h>

typedef __attribute__((ext_vector_type(8))) short  short8_t;
typedef __attribute__((ext_vector_type(4))) float  float4_t;
typedef __attribute__((ext_vector_type(4))) int    int4_t;
typedef __attribute__((ext_vector_type(2))) unsigned int uint2_t;

// f32 -> bf16 RNE (bit-twiddle; prepass/fallback only)
__device__ __forceinline__ unsigned short f2bf(float f) {
    unsigned int u = __builtin_bit_cast(unsigned int, f);
    u += 0x7FFFu + ((u >> 16) & 1u);
    return (unsigned short)(u >> 16);
}
__device__ __forceinline__ unsigned int cvtpk(float a, float b) {
    return (unsigned int)f2bf(a) | ((unsigned int)f2bf(b) << 16);
}
// HW packed convert (no builtin on gfx950)
__device__ __forceinline__ unsigned int cvtpk_hw(float a, float b) {
    unsigned int r;
    asm("v_cvt_pk_bf16_f32 %0, %1, %2" : "=v"(r) : "v"(a), "v"(b));
    return r;
}
// gfx950 cross-lane row swaps (dataflow-ordered)
__device__ __forceinline__ void plane32_swap(unsigned int& a, unsigned int& b) {
    asm("v_permlane32_swap_b32 %0, %1" : "+v"(a), "+v"(b));
}
__device__ __forceinline__ void plane16_swap(unsigned int& a, unsigned int& b) {
    asm("v_permlane16_swap_b32 %0, %1" : "+v"(a), "+v"(b));
}
// pinned 16B load (T4 building block); volatile order vs other volatile asm is exact
__device__ __forceinline__ void gld16(int4_t& d, const void* p) {
    asm volatile("global_load_dwordx4 %0, %1, off" : "=&v"(d) : "v"(p) : "memory");
}
// counted wait: the 6 youngest loads (bf-next 4 + af-next2 2) stay in flight
__device__ __forceinline__ void wait6() {
    asm volatile("s_waitcnt vmcnt(6)" ::: "memory");
    __builtin_amdgcn_sched_barrier(0);
}
__device__ __forceinline__ void wait_all() {
    asm volatile("s_waitcnt vmcnt(0)" ::: "memory");
    __builtin_amdgcn_sched_barrier(0);
}

#define W1ROWS 1152   // 1024 + 128 zero-pad rows (covers dangling tail reads <=1135)

// ---- prepass: W2 -> granule-transposed bf16 W2s[ks][e]; W1 -> bf16 W1b (+zero pad) ----
__global__ void prep_kernel(const float* __restrict__ W2, const float* __restrict__ W1,
                            unsigned short* __restrict__ W2s, unsigned short* __restrict__ W1b) {
    const int bid = blockIdx.x, tid = threadIdx.x;
    if (bid < 128) {
        const int idx = bid * 256 + tid;
        const int e   = idx >> 7;
        const int ks  = idx & 127;
        const float* src = W2 + (size_t)e * 1024 + ks * 8;
        const float4_t v0 = *reinterpret_cast<const float4_t*>(src);
        const float4_t v1 = *reinterpret_cast<const float4_t*>(src + 4);
        int4_t p;
        p[0] = (int)cvtpk(v0[0], v0[1]);
        p[1] = (int)cvtpk(v0[2], v0[3]);
        p[2] = (int)cvtpk(v1[0], v1[1]);
        p[3] = (int)cvtpk(v1[2], v1[3]);
        *reinterpret_cast<int4_t*>(W2s + ((size_t)ks * 256 + e) * 8) = p;
    } else {
        const int base = tid * 32;
        #pragma unroll
        for (int it = 0; it < 8; ++it) {
            const float4_t v = *reinterpret_cast<const float4_t*>(W1 + base + it * 4);
            uint2_t p;
            p[0] = cvtpk(v[0], v[1]);
            p[1] = cvtpk(v[2], v[3]);
            *reinterpret_cast<uint2_t*>(W1b + base + it * 4) = p;
        }
        if (tid < 32) {   // zero pad rows 1024..1151 (1024 shorts)
            #pragma unroll
            for (int it = 0; it < 4; ++it) {
                int4_t z; z[0] = 0; z[1] = 0; z[2] = 0; z[3] = 0;
                *reinterpret_cast<int4_t*>(W1b + 8192 + tid * 32 + it * 8) = z;
            }
        }
    }
}

// ---- fused, zero-LDS-in-loop; 64x64 tiles, K split across 2 waves; h-decoupled ----
// Block = 4 waves = 2 tiles (shared n-tile). Wave (tile tloc, khalf) does 16 chunks of
// K starting at khalf*512. Final f32 reduce via LDS. 1024 blocks -> 3-4 blocks/CU.
template <bool WSOK>
__global__ __launch_bounds__(256, 3)
void ffq_kernel(const float* __restrict__ x,
                const float* __restrict__ theta,
                const float* __restrict__ W1f,
                const unsigned short* __restrict__ W1b,
                const float* __restrict__ W2f,
                const unsigned short* __restrict__ W2s,
                float* __restrict__ out)
{
    __shared__ float red[2][64][65];   // 33.3 KB (65 pad: conflict-free reduce)

    const int tid  = threadIdx.x;
    const int lane = tid & 63;
    const int w    = tid >> 6;
    const int bid  = blockIdx.x;
    const int ntile = bid & 3;
    const int mpair = bid >> 2;
    const int tloc  = w >> 1;          // tile within block
    const int khalf = w & 1;           // K-half of this wave
    const int rowbase = (mpair * 2 + tloc) * 64;
    const int colbase = ntile * 64;
    const int kbase   = khalf * 512;
    const int lr = lane & 15;
    const int G  = lane >> 4;

    // ---- q B-frags (4 m-tiles of 16 rows): lane<16 holds q[row][k=0..7], rest zero ----
    short8_t qf[4];
    #pragma unroll
    for (int mt = 0; mt < 4; ++mt) {
        short8_t v = {0,0,0,0,0,0,0,0};
        if (lane < 16) {
            const float* xp = x + (size_t)(rowbase + mt * 16 + lane) * 256;
            const float4_t x0 = *reinterpret_cast<const float4_t*>(xp);
            const float4_t x1 = *reinterpret_cast<const float4_t*>(xp + 4);
            float qv[8];
            #pragma unroll
            for (int j = 0; j < 4; ++j) {
                qv[j]     = __cosf(x0[j]) * __cosf(theta[j]);
                qv[4 + j] = __cosf(x1[j]) * __cosf(theta[4 + j]);
            }
            int4_t pq;
            pq[0] = (int)cvtpk(qv[0], qv[1]);
            pq[1] = (int)cvtpk(qv[2], qv[3]);
            pq[2] = (int)cvtpk(qv[4], qv[5]);
            pq[3] = (int)cvtpk(qv[6], qv[7]);
            v = __builtin_bit_cast(short8_t, pq);
        }
        qf[mt] = v;
    }

    float4_t acc[4][4];
    #pragma unroll
    for (int i = 0; i < 4; ++i)
        #pragma unroll
        for (int j = 0; j < 4; ++j)
            acc[i][j] = (float4_t){0.f, 0.f, 0.f, 0.f};

    short8_t afrag[4];   // current chunk's A-frags (all indices compile-time)

    // h-chain: af pair -> afrag[0..3] (relu + in-register permlane transpose)
    auto hch = [&](const int4_t& a0, const int4_t& a1) {
        const short8_t af0 = __builtin_bit_cast(short8_t, a0);
        const short8_t af1 = __builtin_bit_cast(short8_t, a1);
        #pragma unroll
        for (int mt = 0; mt < 4; ++mt) {
            const float4_t t0 = __builtin_amdgcn_mfma_f32_16x16x32_bf16(
                af0, qf[mt], (float4_t){0.f, 0.f, 0.f, 0.f}, 0, 0, 0);
            const float4_t t1 = __builtin_amdgcn_mfma_f32_16x16x32_bf16(
                af1, qf[mt], (float4_t){0.f, 0.f, 0.f, 0.f}, 0, 0, 0);
            unsigned int A_ = cvtpk_hw(fmaxf(t0[0], 0.f), fmaxf(t0[1], 0.f));
            unsigned int B_ = cvtpk_hw(fmaxf(t0[2], 0.f), fmaxf(t0[3], 0.f));
            unsigned int C_ = cvtpk_hw(fmaxf(t1[0], 0.f), fmaxf(t1[1], 0.f));
            unsigned int D_ = cvtpk_hw(fmaxf(t1[2], 0.f), fmaxf(t1[3], 0.f));
            plane32_swap(A_, C_);
            plane16_swap(A_, C_);
            plane32_swap(B_, D_);
            plane16_swap(B_, D_);
            int4_t ua;
            ua[0] = (int)A_; ua[1] = (int)B_; ua[2] = (int)C_; ua[3] = (int)D_;
            afrag[mt] = __builtin_bit_cast(short8_t, ua);
        }
    };
    // main GEMM for one chunk: 16 MFMA using afrag + one bf set
    auto mainmm = [&](const int4_t& b0, const int4_t& b1,
                      const int4_t& b2, const int4_t& b3) {
        const short8_t bfr[4] = {
            __builtin_bit_cast(short8_t, b0), __builtin_bit_cast(short8_t, b1),
            __builtin_bit_cast(short8_t, b2), __builtin_bit_cast(short8_t, b3) };
        #pragma unroll
        for (int mt = 0; mt < 4; ++mt)
            #pragma unroll
            for (int cf = 0; cf < 4; ++cf)
                acc[mt][cf] = __builtin_amdgcn_mfma_f32_16x16x32_bf16(
                    afrag[mt], bfr[cf], acc[mt][cf], 0, 0, 0);
    };

    if constexpr (WSOK) {
        auto a_addr = [&](int kc, int t) -> const void* {
            return (const void*)(W1b + (size_t)(kc + t * 16 + lane) * 8);
        };
        auto b_addr = [&](int kc, int cf) -> const void* {
            const int e = colbase + cf * 16 + lr;
            return (const void*)(W2s + (((size_t)(kc >> 3) + G) * 256 + e) * 8);
        };
        int4_t Xa0, Xa1, Ya0, Ya1;            // af sets (even/odd chunk)
        int4_t Ab0, Ab1, Ab2, Ab3;            // bf set A
        int4_t Bb0, Bb1, Bb2, Bb3;            // bf set B

        #define ISSUE_BF(P, K) do { const int kk_ = (K);                    \
            gld16(P##b0, b_addr(kk_, 0)); gld16(P##b1, b_addr(kk_, 1));     \
            gld16(P##b2, b_addr(kk_, 2)); gld16(P##b3, b_addr(kk_, 3)); } while (0)

        // prologue: af(chunk0) -> afrag; then prime queue [bfA(0)4, Ya(1)2]
        gld16(Xa0, a_addr(kbase, 0)); gld16(Xa1, a_addr(kbase, 1));
        wait_all();
        hch(Xa0, Xa1);
        ISSUE_BF(A, kbase);
        gld16(Ya0, a_addr(kbase + 32, 0)); gld16(Ya1, a_addr(kbase + 32, 1));

        #pragma unroll 1
        for (int it = 0; it < 8; ++it) {
            const int c = kbase + it * 64;
            // phase 0: chunk c
            ISSUE_BF(B, c + 32);
            gld16(Xa0, a_addr(c + 64, 0)); gld16(Xa1, a_addr(c + 64, 1));
            wait6();                 // drains bfA(c) + Ya(c+1); leaves [Bb4, Xa2]
            mainmm(Ab0, Ab1, Ab2, Ab3);   // main(c) with afrag(c)
            hch(Ya0, Ya1);                // afrag <- h(c+1)
            // phase 1: chunk c+32
            ISSUE_BF(A, c + 64);
            gld16(Ya0, a_addr(c + 96, 0)); gld16(Ya1, a_addr(c + 96, 1));
            wait6();                 // drains bfB(c+1) + Xa(c+2); leaves [Ab4, Ya2]
            mainmm(Bb0, Bb1, Bb2, Bb3);   // main(c+1)
            hch(Xa0, Xa1);                // afrag <- h(c+2) (tail iter: garbage, unused)
        }
        wait_all();   // land dangling tail prefetches before regalloc reuses their regs
        #undef ISSUE_BF
    } else {
        // fallback (no workspace): compiler-scheduled, correctness-first
        for (int cc = 0; cc < 16; ++cc) {
            const int kc = kbase + cc * 32;
            int4_t a0 = {0,0,0,0}, a1 = {0,0,0,0};
            if (lane < 16) {
                #pragma unroll
                for (int t = 0; t < 2; ++t) {
                    const float* src = W1f + (size_t)(kc + t * 16 + lane) * 8;
                    const float4_t v0 = *reinterpret_cast<const float4_t*>(src);
                    const float4_t v1 = *reinterpret_cast<const float4_t*>(src + 4);
                    int4_t p;
                    p[0] = (int)cvtpk(v0[0], v0[1]);
                    p[1] = (int)cvtpk(v0[2], v0[3]);
                    p[2] = (int)cvtpk(v1[0], v1[1]);
                    p[3] = (int)cvtpk(v1[2], v1[3]);
                    if (t == 0) a0 = p; else a1 = p;
                }
            }
            hch(a0, a1);
            int4_t b[4];
            #pragma unroll
            for (int cf = 0; cf < 4; ++cf) {
                const int e = colbase + cf * 16 + lr;
                const float* p = W2f + (size_t)e * 1024 + kc + G * 8;
                const float4_t v0 = *reinterpret_cast<const float4_t*>(p);
                const float4_t v1 = *reinterpret_cast<const float4_t*>(p + 4);
                int4_t pb;
                pb[0] = (int)cvtpk(v0[0], v0[1]);
                pb[1] = (int)cvtpk(v0[2], v0[3]);
                pb[2] = (int)cvtpk(v1[0], v1[1]);
                pb[3] = (int)cvtpk(v1[2], v1[3]);
                b[cf] = pb;
            }
            mainmm(b[0], b[1], b[2], b[3]);
        }
    }

    // ---- reduce the two K-halves via LDS, then store (khalf 0 wave stores) ----
    if (khalf) {
        #pragma unroll
        for (int mt = 0; mt < 4; ++mt)
            #pragma unroll
            for (int cf = 0; cf < 4; ++cf)
                #pragma unroll
                for (int r = 0; r < 4; ++r)
                    red[tloc][mt * 16 + G * 4 + r][cf * 16 + lr] = acc[mt][cf][r];
    }
    __syncthreads();
    if (!khalf) {
        #pragma unroll
        for (int mt = 0; mt < 4; ++mt)
            #pragma unroll
            for (int cf = 0; cf < 4; ++cf)
                #pragma unroll
                for (int r = 0; r < 4; ++r) {
                    const int gr = rowbase + mt * 16 + G * 4 + r;
                    const int gc = colbase + cf * 16 + lr;
                    out[(size_t)gr * 256 + gc] =
                        acc[mt][cf][r] + red[tloc][mt * 16 + G * 4 + r][cf * 16 + lr];
                }
    }
}

extern "C" void kernel_launch(void* const* d_in, const int* in_sizes, int n_in,
                              void* d_out, int out_size, void* d_ws, size_t ws_size,
                              hipStream_t stream) {
    const float* x     = (const float*)d_in[0];   // [8,4096,256]
    const float* theta = (const float*)d_in[1];   // [8]
    const float* W1    = (const float*)d_in[2];   // [1024,8]
    const float* W2    = (const float*)d_in[3];   // [256,1024]
    float* out = (float*)d_out;                   // [8,4096,256] f32

    const size_t need = (size_t)(256 * 1024 + W1ROWS * 8) * sizeof(unsigned short);
    const bool wsok = (ws_size >= need);

    if (wsok) {
        unsigned short* W2s = (unsigned short*)d_ws;   // 512KB granule-transposed bf16
        unsigned short* W1b = W2s + 256 * 1024;        // 1152x8 bf16 (pad rows zeroed)
        prep_kernel<<<129, 256, 0, stream>>>(W2, W1, W2s, W1b);
        ffq_kernel<true><<<1024, 256, 0, stream>>>(x, theta, nullptr, W1b, nullptr, W2s, out);
    } else {
        ffq_kernel<false><<<1024, 256, 0, stream>>>(x, theta, W1, nullptr, W2, nullptr, out);
    }
}

// Round 13
// 37.829 us; speedup vs baseline: 1.3956x; 1.0572x over previous
//
#include <hip/hip_runtime.h>
#include <hip/hip_bf16.h>

typedef __attribute__((ext_vector_type(8)))  short  short8_t;
typedef __attribute__((ext_vector_type(4)))  float  float4_t;
typedef __attribute__((ext_vector_type(16))) float  f32x16_t;
typedef __attribute__((ext_vector_type(4)))  int    int4_t;
typedef __attribute__((ext_vector_type(2)))  unsigned int uint2_t;

// f32 -> bf16 RNE (bit-twiddle; prepass/fallback)
__device__ __forceinline__ unsigned short f2bf(float f) {
    unsigned int u = __builtin_bit_cast(unsigned int, f);
    u += 0x7FFFu + ((u >> 16) & 1u);
    return (unsigned short)(u >> 16);
}
__device__ __forceinline__ unsigned int cvtpk(float a, float b) {
    return (unsigned int)f2bf(a) | ((unsigned int)f2bf(b) << 16);
}
// HW packed convert (no builtin on gfx950)
__device__ __forceinline__ unsigned int cvtpk_hw(float a, float b) {
    unsigned int r;
    asm("v_cvt_pk_bf16_f32 %0, %1, %2" : "=v"(r) : "v"(a), "v"(b));
    return r;
}
// lane i (i<32) <-> pairs with lane i+32: newX=[X.lo,Y.lo], newY=[X.hi,Y.hi]
__device__ __forceinline__ void plane32_swap(unsigned int& a, unsigned int& b) {
    asm("v_permlane32_swap_b32 %0, %1" : "+v"(a), "+v"(b));
}
// pinned 16B loads (compiler cannot sink/reorder vs volatile asm)
__device__ __forceinline__ void gld16(int4_t& d, const void* p) {
    asm volatile("global_load_dwordx4 %0, %1, off" : "=&v"(d) : "v"(p) : "memory");
}
#define GLD16O(d, p, OFF) \
    asm volatile("global_load_dwordx4 %0, %1, off offset:" OFF : "=&v"(d) : "v"(p) : "memory")
// counted wait: 9 youngest (next-step 8 W2 + 1 af) stay in flight
__device__ __forceinline__ void wait9() {
    asm volatile("s_waitcnt vmcnt(9)" ::: "memory");
    __builtin_amdgcn_sched_barrier(0);
}
__device__ __forceinline__ void wait_all() {
    asm volatile("s_waitcnt vmcnt(0)" ::: "memory");
    __builtin_amdgcn_sched_barrier(0);
}

// ---- prepass ----
// W2t granule layout for 32x32x16 A-frags: granule g = (ks*8+et)*64+lane,
//   value = W2[et*32+(lane&31)][ks*16+(lane>>5)*8 .. +8)  (bf16 x8, 16B)
// W1b: 1024 x 8 bf16 row-major (16B per row granule)
__global__ void prep_kernel(const float* __restrict__ W2, const float* __restrict__ W1,
                            unsigned short* __restrict__ W2t, unsigned short* __restrict__ W1b) {
    const int bid = blockIdx.x, tid = threadIdx.x;
    if (bid < 128) {
        const int g   = bid * 256 + tid;          // 0..32767
        const int l   = g & 63;
        const int pos = g >> 6;                   // ks*8+et
        const int ks  = pos >> 3;
        const int et  = pos & 7;
        const int e   = et * 32 + (l & 31);
        const int f0  = ks * 16 + (l >> 5) * 8;
        const float* src = W2 + (size_t)e * 1024 + f0;
        const float4_t v0 = *reinterpret_cast<const float4_t*>(src);
        const float4_t v1 = *reinterpret_cast<const float4_t*>(src + 4);
        int4_t p;
        p[0] = (int)cvtpk(v0[0], v0[1]);
        p[1] = (int)cvtpk(v0[2], v0[3]);
        p[2] = (int)cvtpk(v1[0], v1[1]);
        p[3] = (int)cvtpk(v1[2], v1[3]);
        *reinterpret_cast<int4_t*>(W2t + (size_t)g * 8) = p;
    } else {
        const int base = tid * 32;                // 8192 floats
        #pragma unroll
        for (int it = 0; it < 8; ++it) {
            const float4_t v = *reinterpret_cast<const float4_t*>(W1 + base + it * 4);
            uint2_t p;
            p[0] = cvtpk(v[0], v[1]);
            p[1] = cvtpk(v[2], v[3]);
            *reinterpret_cast<uint2_t*>(W1b + base + it * 4) = p;
        }
    }
}

// ---- fused, zero-LDS, zero-barrier, 32x32x16 everywhere ----
// Wave = 32 rows x 128 cols, full K=1024. 2048 waves (512 blocks x 4).
// Per 32-f step: 1 h-MFMA + {16 fmax, 8 cvt_pk, 4 permlane32_swap} -> 2 B-frags,
// then 8 main MFMA (2 k-windows x 4 e-tiles) computing out^T[e][m].
template <bool WSOK>
__global__ __launch_bounds__(256, 2)
void ffq_kernel(const float* __restrict__ x,
                const float* __restrict__ theta,
                const float* __restrict__ W1f,
                const unsigned short* __restrict__ W1b,
                const float* __restrict__ W2f,
                const unsigned short* __restrict__ W2t,
                float* __restrict__ out)
{
    const int tid  = threadIdx.x;
    const int lane = tid & 63;
    const int w    = tid >> 6;
    const int bid  = blockIdx.x;
    const int coltile = bid & 1;                  // 2 col-tiles of 128
    const int mtile   = (bid >> 1) * 4 + w;       // 1024 row-tiles of 32
    const int rowbase = mtile * 32;
    const int m  = lane & 31;
    const int hi = lane >> 5;

    // ---- q B-frag: lane<32 holds q[rowbase+m][0..7] bf16; hi lanes ZERO (K pad) ----
    short8_t qf = {0,0,0,0,0,0,0,0};
    if (lane < 32) {
        const float* xp = x + (size_t)(rowbase + m) * 256;
        const float4_t x0 = *reinterpret_cast<const float4_t*>(xp);
        const float4_t x1 = *reinterpret_cast<const float4_t*>(xp + 4);
        float qv[8];
        #pragma unroll
        for (int j = 0; j < 4; ++j) {
            qv[j]     = __cosf(x0[j]) * __cosf(theta[j]);
            qv[4 + j] = __cosf(x1[j]) * __cosf(theta[4 + j]);
        }
        int4_t pq;
        pq[0] = (int)cvtpk(qv[0], qv[1]);
        pq[1] = (int)cvtpk(qv[2], qv[3]);
        pq[2] = (int)cvtpk(qv[4], qv[5]);
        pq[3] = (int)cvtpk(qv[6], qv[7]);
        qf = __builtin_bit_cast(short8_t, pq);
    }

    f32x16_t acc0 = {0}, acc1 = {0}, acc2 = {0}, acc3 = {0};
    #pragma unroll
    for (int i = 0; i < 16; ++i) { acc0[i] = 0.f; acc1[i] = 0.f; acc2[i] = 0.f; acc3[i] = 0.f; }

    short8_t bf0, bf1;   // current step's h-derived B-frags (2 k-windows)

    // h-MFMA + relu + transpose-to-B-frags. D[f][m]: f=(reg&3)+8(reg>>2)+4hi.
    // U[q] pair packs f=(8q+4hi, +1),(+2,+3); swap(U[2w][i],U[2w+1][i]) makes both
    // halves of B-frag word i / i+2 for window w.  (verified 16x16 analog: R5)
    auto htr = [&](short8_t af) {
        const f32x16_t z = acc0 * 0.f;   // cheap zero vec (compiler folds)
        const f32x16_t d = __builtin_amdgcn_mfma_f32_32x32x16_bf16(af, qf, z, 0, 0, 0);
        unsigned int U00 = cvtpk_hw(fmaxf(d[0],  0.f), fmaxf(d[1],  0.f));
        unsigned int U01 = cvtpk_hw(fmaxf(d[2],  0.f), fmaxf(d[3],  0.f));
        unsigned int U10 = cvtpk_hw(fmaxf(d[4],  0.f), fmaxf(d[5],  0.f));
        unsigned int U11 = cvtpk_hw(fmaxf(d[6],  0.f), fmaxf(d[7],  0.f));
        unsigned int U20 = cvtpk_hw(fmaxf(d[8],  0.f), fmaxf(d[9],  0.f));
        unsigned int U21 = cvtpk_hw(fmaxf(d[10], 0.f), fmaxf(d[11], 0.f));
        unsigned int U30 = cvtpk_hw(fmaxf(d[12], 0.f), fmaxf(d[13], 0.f));
        unsigned int U31 = cvtpk_hw(fmaxf(d[14], 0.f), fmaxf(d[15], 0.f));
        plane32_swap(U00, U10);   // -> b0 word0 / word2 (window 0)
        plane32_swap(U01, U11);   // -> b0 word1 / word3
        plane32_swap(U20, U30);   // -> b1 word0 / word2 (window 1)
        plane32_swap(U21, U31);
        int4_t p0; p0[0] = (int)U00; p0[1] = (int)U01; p0[2] = (int)U10; p0[3] = (int)U11;
        int4_t p1; p1[0] = (int)U20; p1[1] = (int)U21; p1[2] = (int)U30; p1[3] = (int)U31;
        bf0 = __builtin_bit_cast(short8_t, p0);
        bf1 = __builtin_bit_cast(short8_t, p1);
    };
    // main: acc[et] += W2frag[w][et] x bf[w]  (8 MFMA)
    auto main8 = [&](const int4_t& r0, const int4_t& r1, const int4_t& r2, const int4_t& r3,
                     const int4_t& r4, const int4_t& r5, const int4_t& r6, const int4_t& r7) {
        acc0 = __builtin_amdgcn_mfma_f32_32x32x16_bf16(__builtin_bit_cast(short8_t, r0), bf0, acc0, 0, 0, 0);
        acc1 = __builtin_amdgcn_mfma_f32_32x32x16_bf16(__builtin_bit_cast(short8_t, r1), bf0, acc1, 0, 0, 0);
        acc2 = __builtin_amdgcn_mfma_f32_32x32x16_bf16(__builtin_bit_cast(short8_t, r2), bf0, acc2, 0, 0, 0);
        acc3 = __builtin_amdgcn_mfma_f32_32x32x16_bf16(__builtin_bit_cast(short8_t, r3), bf0, acc3, 0, 0, 0);
        acc0 = __builtin_amdgcn_mfma_f32_32x32x16_bf16(__builtin_bit_cast(short8_t, r4), bf1, acc0, 0, 0, 0);
        acc1 = __builtin_amdgcn_mfma_f32_32x32x16_bf16(__builtin_bit_cast(short8_t, r5), bf1, acc1, 0, 0, 0);
        acc2 = __builtin_amdgcn_mfma_f32_32x32x16_bf16(__builtin_bit_cast(short8_t, r6), bf1, acc2, 0, 0, 0);
        acc3 = __builtin_amdgcn_mfma_f32_32x32x16_bf16(__builtin_bit_cast(short8_t, r7), bf1, acc3, 0, 0, 0);
    };

    if constexpr (WSOK) {
        // per-lane byte bases
        const char* W2b = (const char*)W2t + (size_t)coltile * 4096 + (size_t)lane * 16;
        const char* W1a = (const char*)W1b + (size_t)m * 16;

        int4_t c0,c1,c2,c3,c4,c5,c6,c7;     // W2 frags, current step
        int4_t n0,n1,n2,n3,n4,n5,n6,n7;     // W2 frags, next step
        int4_t afA, afB;

        #define ISSUE_W2(R0,R1,R2,R3,R4,R5,R6,R7, S) do {                        \
            const char* p0_ = W2b + ((size_t)((S) & 31) << 14);                  \
            const char* p1_ = p0_ + 8192;                                        \
            GLD16O(R0, p0_, "0");    GLD16O(R1, p0_, "1024");                    \
            GLD16O(R2, p0_, "2048"); GLD16O(R3, p0_, "3072");                    \
            GLD16O(R4, p1_, "0");    GLD16O(R5, p1_, "1024");                    \
            GLD16O(R6, p1_, "2048"); GLD16O(R7, p1_, "3072"); } while (0)
        #define ISSUE_AF(R, S) gld16(R, W1a + ((size_t)((S) & 31) << 9))

        // prologue
        ISSUE_AF(afA, 0);
        wait_all();
        ISSUE_AF(afB, 1);
        htr(__builtin_bit_cast(short8_t, afA));   // bf for step 0
        ISSUE_W2(c0,c1,c2,c3,c4,c5,c6,c7, 0);
        // invariant entering each step: 9 outstanding = [W2(cur step) x8, af(step+1)]

        #pragma unroll 1
        for (int k = 0; k < 16; ++k) {
            const int s = k * 2;
            // even step s
            ISSUE_W2(n0,n1,n2,n3,n4,n5,n6,n7, s + 1);
            ISSUE_AF(afA, s + 2);
            wait9();                               // W2(s) + af(s+1) landed
            main8(c0,c1,c2,c3,c4,c5,c6,c7);
            htr(__builtin_bit_cast(short8_t, afB));   // bf for step s+1
            // odd step s+1
            ISSUE_W2(c0,c1,c2,c3,c4,c5,c6,c7, s + 2);
            ISSUE_AF(afB, s + 3);
            wait9();                               // W2(s+1) + af(s+2) landed
            main8(n0,n1,n2,n3,n4,n5,n6,n7);
            htr(__builtin_bit_cast(short8_t, afA));   // bf for step s+2 (tail: unused)
        }
        wait_all();   // land dangling wrap prefetches before regalloc reuses their regs
        #undef ISSUE_W2
        #undef ISSUE_AF
    } else {
        // fallback: same math, plain compiler-scheduled loads + on-the-fly cvt
        for (int s = 0; s < 32; ++s) {
            const float* ws = W1f + (size_t)(s * 32 + m) * 8;
            const float4_t a0 = *reinterpret_cast<const float4_t*>(ws);
            const float4_t a1 = *reinterpret_cast<const float4_t*>(ws + 4);
            int4_t pa;
            pa[0] = (int)cvtpk(a0[0], a0[1]);
            pa[1] = (int)cvtpk(a0[2], a0[3]);
            pa[2] = (int)cvtpk(a1[0], a1[1]);
            pa[3] = (int)cvtpk(a1[2], a1[3]);
            htr(__builtin_bit_cast(short8_t, pa));
            int4_t fr[8];
            #pragma unroll
            for (int ww = 0; ww < 2; ++ww)
                #pragma unroll
                for (int et = 0; et < 4; ++et) {
                    const int e = coltile * 128 + et * 32 + m;
                    const float* p = W2f + (size_t)e * 1024 + (s * 32 + ww * 16) + hi * 8;
                    const float4_t v0 = *reinterpret_cast<const float4_t*>(p);
                    const float4_t v1 = *reinterpret_cast<const float4_t*>(p + 4);
                    int4_t pb;
                    pb[0] = (int)cvtpk(v0[0], v0[1]);
                    pb[1] = (int)cvtpk(v0[2], v0[3]);
                    pb[2] = (int)cvtpk(v1[0], v1[1]);
                    pb[3] = (int)cvtpk(v1[2], v1[3]);
                    fr[ww * 4 + et] = pb;
                }
            main8(fr[0], fr[1], fr[2], fr[3], fr[4], fr[5], fr[6], fr[7]);
        }
    }

    // ---- epilogue: out^T store. D[e][m]: col m=lane&31, e=(reg&3)+8(reg>>2)+4hi ----
    {
        float* orow = out + (size_t)(rowbase + m) * 256 + coltile * 128 + hi * 4;
        #define STORE_ET(ACC, ET) do {                                           \
            _Pragma("unroll")                                                    \
            for (int rq = 0; rq < 4; ++rq) {                                     \
                float4_t v;                                                      \
                v[0] = ACC[4*rq+0]; v[1] = ACC[4*rq+1];                          \
                v[2] = ACC[4*rq+2]; v[3] = ACC[4*rq+3];                          \
                *reinterpret_cast<float4_t*>(orow + (ET) * 32 + rq * 8) = v;     \
            } } while (0)
        STORE_ET(acc0, 0);
        STORE_ET(acc1, 1);
        STORE_ET(acc2, 2);
        STORE_ET(acc3, 3);
        #undef STORE_ET
    }
}

extern "C" void kernel_launch(void* const* d_in, const int* in_sizes, int n_in,
                              void* d_out, int out_size, void* d_ws, size_t ws_size,
                              hipStream_t stream) {
    const float* x     = (const float*)d_in[0];   // [8,4096,256]
    const float* theta = (const float*)d_in[1];   // [8]
    const float* W1    = (const float*)d_in[2];   // [1024,8]
    const float* W2    = (const float*)d_in[3];   // [256,1024]
    float* out = (float*)d_out;                   // [8,4096,256] f32

    const size_t need = (size_t)(256 * 1024 + 1024 * 8) * sizeof(unsigned short);
    const bool wsok = (ws_size >= need);

    if (wsok) {
        unsigned short* W2t = (unsigned short*)d_ws;   // 512KB, 32x32x16-A granule layout
        unsigned short* W1b = W2t + 256 * 1024;        // 16KB bf16
        prep_kernel<<<129, 256, 0, stream>>>(W2, W1, W2t, W1b);
        ffq_kernel<true><<<512, 256, 0, stream>>>(x, theta, nullptr, W1b, nullptr, W2t, out);
    } else {
        ffq_kernel<false><<<512, 256, 0, stream>>>(x, theta, W1, nullptr, W2, nullptr, out);
    }
}